// Round 1
// baseline (187.947 us; speedup 1.0000x reference)
//
#include <hip/hip_runtime.h>
#include <math.h>

#define NB 8

__global__ __launch_bounds__(256) void edge_embed_kernel(
    const float* __restrict__ vec,
    const float* __restrict__ len,
    const float* __restrict__ w,   // [4][8][8]
    float* __restrict__ out,       // [E][128]
    int E)
{
    int e = blockIdx.x * blockDim.x + threadIdx.x;
    if (e >= E) return;

    float x = vec[3*e+0];
    float y = vec[3*e+1];
    float z = vec[3*e+2];
    float r = len[e];

    // --- normalized direction (matches reference: vec / ||vec||) ---
    float rinv_n = rsqrtf(x*x + y*y + z*z);
    float nx = x*rinv_n, ny = y*rinv_n, nz = z*rinv_n;
    float x2 = nx*nx, y2 = ny*ny, z2 = nz*nz;

    // --- envelope: 1 - 28 u^6 + 48 u^7 - 21 u^8, zero for u>=1 (p=6) ---
    float u  = r * 0.2f;              // r / R_MAX
    float u2 = u*u;
    float u3 = u2*u;
    float u6 = u3*u3;
    float env = 1.0f - 28.0f*u6 + 48.0f*u6*u - 21.0f*u6*u2;
    env = (u < 1.0f) ? env : 0.0f;

    // fold sqrt(2/R_MAX) * (1/r) * env * (1/sqrt(NB)) into one factor
    float invr = 1.0f / r;
    float f = 0.6324555320336759f    // sqrt(2/5)
            * 0.35355339059327373f   // 1/sqrt(8)
            * invr * env;

    // --- bessel sines via Chebyshev recurrence: sin(n*kr), n=1..8 ---
    float kr = 0.6283185307179586f * r;   // pi/5 * r
    float s1, c1;
    __sincosf(kr, &s1, &c1);
    float twoc = 2.0f * c1;
    float rad[NB];
    rad[0] = s1;
    rad[1] = twoc * s1;
    #pragma unroll
    for (int n = 2; n < NB; ++n) rad[n] = twoc*rad[n-1] - rad[n-2];
    #pragma unroll
    for (int n = 0; n < NB; ++n) rad[n] *= f;

    // --- per-l matvec: sc[l][c] = sum_b rad[b] * w[l][b][c] ---
    // w offsets are compile-time uniform -> scalar loads (constant cache)
    float sc[4][8];
    #pragma unroll
    for (int l = 0; l < 4; ++l) {
        #pragma unroll
        for (int c = 0; c < 8; ++c) {
            float acc = 0.0f;
            #pragma unroll
            for (int b = 0; b < NB; ++b)
                acc = fmaf(rad[b], w[l*64 + b*8 + c], acc);
            sc[l][c] = acc;
        }
    }

    // --- spherical harmonics (e3nn component-normalized, y polar) ---
    float Y1x = 1.7320508075688772f * nx;   // sqrt(3) x
    float Y1y = 1.7320508075688772f * ny;
    float Y1z = 1.7320508075688772f * nz;

    float Y4 = 3.872983346207417f * nx * nz;                 // sqrt(15) xz
    float Y5 = 3.872983346207417f * nx * ny;                 // sqrt(15) xy
    float Y6 = 2.23606797749979f  * (y2 - 0.5f*(x2 + z2));   // sqrt(5)(...)
    float Y7 = 3.872983346207417f * ny * nz;                 // sqrt(15) yz
    float Y8 = 1.9364916731037085f * (z2 - x2);              // sqrt(15)/2

    const float c3 = 2.6457513110645907f;  // sqrt(7)
    float Y9  = c3 * 0.7905694150420949f * nz * (3.0f*x2 - z2);  // sqrt(10)/4
    float Y10 = c3 * 3.872983346207417f  * nx * ny * nz;         // sqrt(15)
    float Y11 = c3 * 0.6123724356957945f * nz * (5.0f*y2 - 1.0f);// sqrt(6)/4
    float Y12 = c3 * 0.5f                * ny * (5.0f*y2 - 3.0f);
    float Y13 = c3 * 0.6123724356957945f * nx * (5.0f*y2 - 1.0f);
    float Y14 = c3 * 1.9364916731037085f * ny * (x2 - z2);       // sqrt(15)/2
    float Y15 = c3 * 0.7905694150420949f * nx * (x2 - 3.0f*z2);  // sqrt(10)/4

    float Y[16] = {1.0f, Y1x, Y1y, Y1z,
                   Y4, Y5, Y6, Y7, Y8,
                   Y9, Y10, Y11, Y12, Y13, Y14, Y15};

    // --- outputs: [8 | 24 | 40 | 56] = 128 floats, written as 32 float4 ---
    float4* o = (float4*)(out + (size_t)e * 128);
    auto val = [&](int j) -> float {
        if (j < 8)  return sc[0][j];                              // Y[0] = 1
        if (j < 32) { int t = j - 8;  return sc[1][t/3] * Y[1 + t%3]; }
        if (j < 72) { int t = j - 32; return sc[2][t/5] * Y[4 + t%5]; }
        { int t = j - 72; return sc[3][t/7] * Y[9 + t%7]; }
    };
    #pragma unroll
    for (int q = 0; q < 32; ++q) {
        float4 v = make_float4(val(4*q+0), val(4*q+1), val(4*q+2), val(4*q+3));
        o[q] = v;
    }
}

extern "C" void kernel_launch(void* const* d_in, const int* in_sizes, int n_in,
                              void* d_out, int out_size, void* d_ws, size_t ws_size,
                              hipStream_t stream) {
    const float* vec = (const float*)d_in[0];   // [E,3]
    const float* len = (const float*)d_in[1];   // [E]
    const float* w   = (const float*)d_in[2];   // [4,8,8]
    float* out = (float*)d_out;                 // [E,128]
    int E = in_sizes[1];
    int blocks = (E + 255) / 256;
    hipLaunchKernelGGL(edge_embed_kernel, dim3(blocks), dim3(256), 0, stream,
                       vec, len, w, out, E);
}

// Round 2
// 107.358 us; speedup vs baseline: 1.7507x; 1.7507x over previous
//
#include <hip/hip_runtime.h>
#include <math.h>

#define NB 8

__global__ __launch_bounds__(256) void edge_embed_kernel(
    const float* __restrict__ vec,
    const float* __restrict__ len,
    const float* __restrict__ w,   // [4][8][8]
    float* __restrict__ out,       // [E][128]
    int E)
{
    // Per-wave staging slab: 64 edges x (32 floats data + 4 pad).
    // Row stride 36 floats = 9 quads (odd) -> both LDS write and read phases
    // spread uniformly over the 8 16B-superbanks (no excess conflicts).
    __shared__ float lds[4][64][36];   // 36,864 B -> 4 blocks/CU

    const int tid    = threadIdx.x;
    const int wave   = tid >> 6;
    const int lane   = tid & 63;
    const int base_e = blockIdx.x * 256 + wave * 64;
    if (base_e >= E) return;           // whole-wave guard (no block barriers used)
    const int e = base_e + lane;

    float x = 1.0f, y = 0.0f, z = 0.0f, r = 1.0f;
    if (e < E) {
        x = vec[3*e+0];
        y = vec[3*e+1];
        z = vec[3*e+2];
        r = len[e];
    }

    // --- normalized direction ---
    float rinv_n = rsqrtf(x*x + y*y + z*z);
    float nx = x*rinv_n, ny = y*rinv_n, nz = z*rinv_n;
    float x2 = nx*nx, y2 = ny*ny, z2 = nz*nz;

    // --- envelope: 1 - 28 u^6 + 48 u^7 - 21 u^8, zero for u>=1 (p=6) ---
    float u  = r * 0.2f;
    float u2 = u*u;
    float u6 = (u2*u)*(u2*u);
    float env = 1.0f - 28.0f*u6 + 48.0f*u6*u - 21.0f*u6*u2;
    env = (u < 1.0f) ? env : 0.0f;

    // fold sqrt(2/R_MAX) * (1/r) * env * (1/sqrt(NB))
    float f = 0.6324555320336759f * 0.35355339059327373f * (1.0f / r) * env;

    // --- bessel sines via Chebyshev recurrence ---
    float kr = 0.6283185307179586f * r;   // pi/5 * r
    float s1, c1;
    __sincosf(kr, &s1, &c1);
    float twoc = 2.0f * c1;
    float rad[NB];
    rad[0] = s1;
    rad[1] = twoc * s1;
    #pragma unroll
    for (int n = 2; n < NB; ++n) rad[n] = twoc*rad[n-1] - rad[n-2];
    #pragma unroll
    for (int n = 0; n < NB; ++n) rad[n] *= f;

    // --- per-l matvec via scalar (constant-cache) weight reads ---
    float sc[4][8];
    #pragma unroll
    for (int l = 0; l < 4; ++l) {
        #pragma unroll
        for (int c = 0; c < 8; ++c) {
            float acc = 0.0f;
            #pragma unroll
            for (int b = 0; b < NB; ++b)
                acc = fmaf(rad[b], w[l*64 + b*8 + c], acc);
            sc[l][c] = acc;
        }
    }

    // --- spherical harmonics (e3nn component-normalized, y polar) ---
    float Y1x = 1.7320508075688772f * nx;
    float Y1y = 1.7320508075688772f * ny;
    float Y1z = 1.7320508075688772f * nz;

    float Y4 = 3.872983346207417f * nx * nz;
    float Y5 = 3.872983346207417f * nx * ny;
    float Y6 = 2.23606797749979f  * (y2 - 0.5f*(x2 + z2));
    float Y7 = 3.872983346207417f * ny * nz;
    float Y8 = 1.9364916731037085f * (z2 - x2);

    const float c3 = 2.6457513110645907f;  // sqrt(7)
    float Y9  = c3 * 0.7905694150420949f * nz * (3.0f*x2 - z2);
    float Y10 = c3 * 3.872983346207417f  * nx * ny * nz;
    float Y11 = c3 * 0.6123724356957945f * nz * (5.0f*y2 - 1.0f);
    float Y12 = c3 * 0.5f                * ny * (5.0f*y2 - 3.0f);
    float Y13 = c3 * 0.6123724356957945f * nx * (5.0f*y2 - 1.0f);
    float Y14 = c3 * 1.9364916731037085f * ny * (x2 - z2);
    float Y15 = c3 * 0.7905694150420949f * nx * (x2 - 3.0f*z2);

    float Y[16] = {1.0f, Y1x, Y1y, Y1z,
                   Y4, Y5, Y6, Y7, Y8,
                   Y9, Y10, Y11, Y12, Y13, Y14, Y15};

    auto val = [&](int j) -> float {
        if (j < 8)  return sc[0][j];
        if (j < 32) { int t = j - 8;  return sc[1][t/3] * Y[1 + t%3]; }
        if (j < 72) { int t = j - 32; return sc[2][t/5] * Y[4 + t%5]; }
        { int t = j - 72; return sc[3][t/7] * Y[9 + t%7]; }
    };

    float* slab = &lds[wave][0][0];

    // 4 passes; each stages 32 floats/edge for 64 edges, then stores them
    // line-coalesced: one store instruction = 8 edges x 128B contiguous
    // chunks = 16 fully-covered 64B lines.
    #pragma unroll
    for (int p = 0; p < 4; ++p) {
        #pragma unroll
        for (int q = 0; q < 8; ++q) {
            int j = p*32 + q*4;
            float4 v = make_float4(val(j), val(j+1), val(j+2), val(j+3));
            *(float4*)(slab + lane*36 + q*4) = v;
        }
        // wave-private slab: per-wave LDS ordering + explicit fence
        asm volatile("s_waitcnt lgkmcnt(0)" ::: "memory");

        #pragma unroll
        for (int t = 0; t < 8; ++t) {
            int g  = t*64 + lane;
            int el = g >> 3;            // edge within slab
            int q  = g & 7;             // quad within pass
            float4 v = *(const float4*)(slab + el*36 + q*4);
            int ge = base_e + el;
            if (ge < E)
                *(float4*)(out + (size_t)ge*128 + p*32 + q*4) = v;
        }
        // reads must retire before next pass overwrites the slab
        asm volatile("s_waitcnt lgkmcnt(0)" ::: "memory");
    }
}

extern "C" void kernel_launch(void* const* d_in, const int* in_sizes, int n_in,
                              void* d_out, int out_size, void* d_ws, size_t ws_size,
                              hipStream_t stream) {
    const float* vec = (const float*)d_in[0];   // [E,3]
    const float* len = (const float*)d_in[1];   // [E]
    const float* w   = (const float*)d_in[2];   // [4,8,8]
    float* out = (float*)d_out;                 // [E,128]
    int E = in_sizes[1];
    int blocks = (E + 255) / 256;
    hipLaunchKernelGGL(edge_embed_kernel, dim3(blocks), dim3(256), 0, stream,
                       vec, len, w, out, E);
}

// Round 4
// 99.233 us; speedup vs baseline: 1.8940x; 1.0819x over previous
//
#include <hip/hip_runtime.h>
#include <math.h>

#define NB 8

typedef float fx4 __attribute__((ext_vector_type(4)));

__global__ __launch_bounds__(256) void edge_embed_kernel(
    const float* __restrict__ vec,
    const float* __restrict__ len,
    const float* __restrict__ w,   // [4][8][8]
    float* __restrict__ out,       // [E][128]
    int E)
{
    // Per-wave staging slab: 64 edges x 32 floats, XOR quad-swizzle
    // (quad' = quad ^ (row&7)) -> conflict-free (2 lanes/bank) on both the
    // write phase and the read phase, with no pad. 32 KB/block -> 5 blocks/CU.
    __shared__ float lds[4][64][32];

    const int tid    = threadIdx.x;
    const int wave   = tid >> 6;
    const int lane   = tid & 63;
    const int base_e = blockIdx.x * 256 + wave * 64;
    if (base_e >= E) return;           // whole-wave guard (no block barriers)
    const int e = base_e + lane;

    float x = 1.0f, y = 0.0f, z = 0.0f, r = 1.0f;
    if (e < E) {
        x = vec[3*e+0];
        y = vec[3*e+1];
        z = vec[3*e+2];
        r = len[e];
    }

    // --- normalized direction ---
    float rinv_n = rsqrtf(x*x + y*y + z*z);
    float nx = x*rinv_n, ny = y*rinv_n, nz = z*rinv_n;
    float x2 = nx*nx, y2 = ny*ny, z2 = nz*nz;

    // --- envelope: 1 - 28 u^6 + 48 u^7 - 21 u^8, zero for u>=1 (p=6) ---
    float u  = r * 0.2f;
    float u2 = u*u;
    float u6 = (u2*u)*(u2*u);
    float env = 1.0f - 28.0f*u6 + 48.0f*u6*u - 21.0f*u6*u2;
    env = (u < 1.0f) ? env : 0.0f;

    // fold sqrt(2/R_MAX) * (1/r) * env * (1/sqrt(NB))
    float f = 0.6324555320336759f * 0.35355339059327373f * (1.0f / r) * env;

    // --- bessel sines via Chebyshev recurrence ---
    float kr = 0.6283185307179586f * r;   // pi/5 * r
    float s1, c1;
    __sincosf(kr, &s1, &c1);
    float twoc = 2.0f * c1;
    float rad[NB];
    rad[0] = s1;
    rad[1] = twoc * s1;
    #pragma unroll
    for (int n = 2; n < NB; ++n) rad[n] = twoc*rad[n-1] - rad[n-2];
    #pragma unroll
    for (int n = 0; n < NB; ++n) rad[n] *= f;

    // --- per-l matvec via scalar (constant-cache) weight reads ---
    float sc[4][8];
    #pragma unroll
    for (int l = 0; l < 4; ++l) {
        #pragma unroll
        for (int c = 0; c < 8; ++c) {
            float acc = 0.0f;
            #pragma unroll
            for (int b = 0; b < NB; ++b)
                acc = fmaf(rad[b], w[l*64 + b*8 + c], acc);
            sc[l][c] = acc;
        }
    }

    // --- spherical harmonics (e3nn component-normalized, y polar) ---
    float Y1x = 1.7320508075688772f * nx;
    float Y1y = 1.7320508075688772f * ny;
    float Y1z = 1.7320508075688772f * nz;

    float Y4 = 3.872983346207417f * nx * nz;
    float Y5 = 3.872983346207417f * nx * ny;
    float Y6 = 2.23606797749979f  * (y2 - 0.5f*(x2 + z2));
    float Y7 = 3.872983346207417f * ny * nz;
    float Y8 = 1.9364916731037085f * (z2 - x2);

    const float c3 = 2.6457513110645907f;  // sqrt(7)
    float Y9  = c3 * 0.7905694150420949f * nz * (3.0f*x2 - z2);
    float Y10 = c3 * 3.872983346207417f  * nx * ny * nz;
    float Y11 = c3 * 0.6123724356957945f * nz * (5.0f*y2 - 1.0f);
    float Y12 = c3 * 0.5f                * ny * (5.0f*y2 - 3.0f);
    float Y13 = c3 * 0.6123724356957945f * nx * (5.0f*y2 - 1.0f);
    float Y14 = c3 * 1.9364916731037085f * ny * (x2 - z2);
    float Y15 = c3 * 0.7905694150420949f * nx * (x2 - 3.0f*z2);

    float Y[16] = {1.0f, Y1x, Y1y, Y1z,
                   Y4, Y5, Y6, Y7, Y8,
                   Y9, Y10, Y11, Y12, Y13, Y14, Y15};

    auto val = [&](int j) -> float {
        if (j < 8)  return sc[0][j];
        if (j < 32) { int t = j - 8;  return sc[1][t/3] * Y[1 + t%3]; }
        if (j < 72) { int t = j - 32; return sc[2][t/5] * Y[4 + t%5]; }
        { int t = j - 72; return sc[3][t/7] * Y[9 + t%7]; }
    };

    float* slab = &lds[wave][0][0];

    // E and wave base are both multiples of 64 in practice -> one uniform
    // branch replaces 32 per-lane-predicated stores.
    const bool full = (base_e + 64 <= E);

    #pragma unroll
    for (int p = 0; p < 4; ++p) {
        // stage 32 floats/edge, swizzled quads
        #pragma unroll
        for (int q = 0; q < 8; ++q) {
            int j = p*32 + q*4;
            fx4 v = {val(j), val(j+1), val(j+2), val(j+3)};
            *(fx4*)(slab + lane*32 + ((q ^ (lane & 7)) * 4)) = v;
        }
        asm volatile("s_waitcnt lgkmcnt(0)" ::: "memory");

        // read transposed: lane covers edge el = t*8 + (lane>>3), quad lane&7
        #pragma unroll
        for (int t = 0; t < 8; ++t) {
            int el = t*8 + (lane >> 3);
            int q  = lane & 7;
            fx4 v = *(const fx4*)(slab + el*32 + (((lane & 7) ^ (lane >> 3)) * 4));
            if (full) {
                __builtin_nontemporal_store(v,
                    (fx4*)(out + (size_t)(base_e + el)*128 + p*32 + q*4));
            } else {
                int ge = base_e + el;
                if (ge < E)
                    __builtin_nontemporal_store(v,
                        (fx4*)(out + (size_t)ge*128 + p*32 + q*4));
            }
        }
        // reads must retire before next pass overwrites the slab
        asm volatile("s_waitcnt lgkmcnt(0)" ::: "memory");
    }
}

extern "C" void kernel_launch(void* const* d_in, const int* in_sizes, int n_in,
                              void* d_out, int out_size, void* d_ws, size_t ws_size,
                              hipStream_t stream) {
    const float* vec = (const float*)d_in[0];   // [E,3]
    const float* len = (const float*)d_in[1];   // [E]
    const float* w   = (const float*)d_in[2];   // [4,8,8]
    float* out = (float*)d_out;                 // [E,128]
    int E = in_sizes[1];
    int blocks = (E + 255) / 256;
    hipLaunchKernelGGL(edge_embed_kernel, dim3(blocks), dim3(256), 0, stream,
                       vec, len, w, out, E);
}